// Round 4
// baseline (277.409 us; speedup 1.0000x reference)
//
#include <hip/hip_runtime.h>

#define NBINS 201
#define NCH 5
#define NTOT (NCH * NBINS)          // 1005
#define B_ELEMS (4194304 * 5)       // 20971520 total elements
#define NVEC (B_ELEMS / 4)          // 5242880 float4s
#define BLOCK 256
#define GRID 2560                   // 655360 threads; 4*T % 5 == 0 -> channel phase const
#define TTHREADS (GRID * BLOCK)     // 655360
#define NITER (NVEC / TTHREADS)     // 8

// ws layout (floats): [0..1004] weight table, [1008] gg sink, [1009] copy sink

__global__ __launch_bounds__(512) void k_table(const int* __restrict__ counts,
                                               float* __restrict__ wsf) {
    __shared__ float s_tot[NCH];
    int tid = threadIdx.x, wv = tid >> 6, ln = tid & 63;
    if (wv < NCH) {
        long long s = 0;
        for (int i = ln; i < NBINS; i += 64) s += counts[wv * NBINS + i];
        #pragma unroll
        for (int o = 32; o > 0; o >>= 1) s += __shfl_down(s, o, 64);
        if (ln == 0) s_tot[wv] = (float)s;
    }
    __syncthreads();
    for (int i = tid; i < NTOT; i += 512)
        wsf[i] = 1.0f - (float)counts[i] / s_tot[i / NBINS];
    if (tid < 2) wsf[1008 + tid] = 0.0f;   // zero probe sinks
}

__device__ __forceinline__ float wproc(float x, float t, const float* w, const int* rb, int j) {
    float kf = rintf(x * 10.0f);           // half-to-even == jnp.round
    float wt = 1.0f;
    if (kf >= -100.0f && kf <= 100.0f) wt = w[rb[j] + (int)kf];
    float d = x - t;
    return wt * d * d;
}

__device__ __forceinline__ void block_reduce_atomic(float acc, float scale, float* dst) {
    __shared__ float s_part[4];
    #pragma unroll
    for (int o = 32; o > 0; o >>= 1) acc += __shfl_down(acc, o, 64);
    int lane = threadIdx.x & 63, wid = threadIdx.x >> 6;
    if (lane == 0) s_part[wid] = acc;
    __syncthreads();
    if (threadIdx.x == 0)
        atomicAdd(dst, (s_part[0] + s_part[1] + s_part[2] + s_part[3]) * scale);
}

// ---- main (correct output): LDS table, streaming 4-loads/trip ----
__global__ __launch_bounds__(BLOCK) void k_main(const float4* __restrict__ in4,
                                                const float4* __restrict__ tg4,
                                                const float* __restrict__ wsf,
                                                float* __restrict__ out) {
    __shared__ float s_w[NTOT];
    for (int i = threadIdx.x; i < NTOT; i += BLOCK) s_w[i] = wsf[i];
    __syncthreads();

    int g = blockIdx.x * BLOCK + threadIdx.x;
    int c0 = (4 * g) % 5;
    int rb[4];
    #pragma unroll
    for (int j = 0; j < 4; ++j) { int c = c0 + j; if (c >= NCH) c -= NCH; rb[j] = c * NBINS + 100; }

    float acc = 0.0f;
    #pragma unroll 1
    for (int it = 0; it < NITER; it += 2) {
        float4 a0 = in4[g + it * TTHREADS],       b0 = tg4[g + it * TTHREADS];
        float4 a1 = in4[g + (it + 1) * TTHREADS], b1 = tg4[g + (it + 1) * TTHREADS];
        acc += wproc(a0.x, b0.x, s_w, rb, 0); acc += wproc(a0.y, b0.y, s_w, rb, 1);
        acc += wproc(a0.z, b0.z, s_w, rb, 2); acc += wproc(a0.w, b0.w, s_w, rb, 3);
        acc += wproc(a1.x, b1.x, s_w, rb, 0); acc += wproc(a1.y, b1.y, s_w, rb, 1);
        acc += wproc(a1.z, b1.z, s_w, rb, 2); acc += wproc(a1.w, b1.w, s_w, rb, 3);
    }
    block_reduce_atomic(acc, 1.0f / (float)B_ELEMS, out);
}

// ---- probe: weights via global gather from 4KB L1-resident table ----
__global__ __launch_bounds__(BLOCK) void k_gg(const float4* __restrict__ in4,
                                              const float4* __restrict__ tg4,
                                              const float* __restrict__ wsf,
                                              float* __restrict__ sink) {
    int g = blockIdx.x * BLOCK + threadIdx.x;
    int c0 = (4 * g) % 5;
    int rb[4];
    #pragma unroll
    for (int j = 0; j < 4; ++j) { int c = c0 + j; if (c >= NCH) c -= NCH; rb[j] = c * NBINS + 100; }

    float acc = 0.0f;
    #pragma unroll 1
    for (int it = 0; it < NITER; it += 2) {
        float4 a0 = in4[g + it * TTHREADS],       b0 = tg4[g + it * TTHREADS];
        float4 a1 = in4[g + (it + 1) * TTHREADS], b1 = tg4[g + (it + 1) * TTHREADS];
        acc += wproc(a0.x, b0.x, wsf, rb, 0); acc += wproc(a0.y, b0.y, wsf, rb, 1);
        acc += wproc(a0.z, b0.z, wsf, rb, 2); acc += wproc(a0.w, b0.w, wsf, rb, 3);
        acc += wproc(a1.x, b1.x, wsf, rb, 0); acc += wproc(a1.y, b1.y, wsf, rb, 1);
        acc += wproc(a1.z, b1.z, wsf, rb, 2); acc += wproc(a1.w, b1.w, wsf, rb, 3);
    }
    block_reduce_atomic(acc, 1.0f / (float)B_ELEMS, sink);
}

// ---- probe: pure bandwidth (no weight path at all) ----
__global__ __launch_bounds__(BLOCK) void k_copy(const float4* __restrict__ in4,
                                                const float4* __restrict__ tg4,
                                                float* __restrict__ sink) {
    int g = blockIdx.x * BLOCK + threadIdx.x;
    float acc = 0.0f;
    #pragma unroll 1
    for (int it = 0; it < NITER; it += 2) {
        float4 a0 = in4[g + it * TTHREADS],       b0 = tg4[g + it * TTHREADS];
        float4 a1 = in4[g + (it + 1) * TTHREADS], b1 = tg4[g + (it + 1) * TTHREADS];
        float d0x = a0.x - b0.x, d0y = a0.y - b0.y, d0z = a0.z - b0.z, d0w = a0.w - b0.w;
        float d1x = a1.x - b1.x, d1y = a1.y - b1.y, d1z = a1.z - b1.z, d1w = a1.w - b1.w;
        acc = fmaf(d0x, d0x, acc); acc = fmaf(d0y, d0y, acc);
        acc = fmaf(d0z, d0z, acc); acc = fmaf(d0w, d0w, acc);
        acc = fmaf(d1x, d1x, acc); acc = fmaf(d1y, d1y, acc);
        acc = fmaf(d1z, d1z, acc); acc = fmaf(d1w, d1w, acc);
    }
    block_reduce_atomic(acc, 1.0f / (float)B_ELEMS, sink);
}

extern "C" void kernel_launch(void* const* d_in, const int* in_sizes, int n_in,
                              void* d_out, int out_size, void* d_ws, size_t ws_size,
                              hipStream_t stream) {
    const float4* in4   = (const float4*)d_in[0];
    const float4* tg4   = (const float4*)d_in[1];
    const int*    counts = (const int*)d_in[3];
    float* wsf = (float*)d_ws;

    hipMemsetAsync(d_out, 0, sizeof(float), stream);
    k_table<<<1, 512, 0, stream>>>(counts, wsf);
    k_main <<<GRID, BLOCK, 0, stream>>>(in4, tg4, wsf, (float*)d_out);
    k_gg   <<<GRID, BLOCK, 0, stream>>>(in4, tg4, wsf, &wsf[1008]);
    k_copy <<<GRID, BLOCK, 0, stream>>>(in4, tg4, &wsf[1009]);
}

// Round 14
// 195.196 us; speedup vs baseline: 1.4212x; 1.4212x over previous
//
#include <hip/hip_runtime.h>

#define NBINS 201
#define NCH 5
#define NTOT (NCH * NBINS)          // 1005
#define B_ELEMS (4194304 * 5)       // 20971520 total elements
#define NVEC (B_ELEMS / 4)          // 5242880 float4s
#define BLOCK 256
#define GRID 2560                   // 10 blocks/CU exactly; 4*TTH % 5 == 0
#define TTH (GRID * BLOCK)          // 655360 threads
#define NITER (NVEC / TTH)          // 8 float4-pairs per thread

// ws layout (floats): [0..1004] prebuilt weight table

__global__ __launch_bounds__(512) void k_table(const int* __restrict__ counts,
                                               float* __restrict__ wsf) {
    __shared__ float s_tot[NCH];
    int tid = threadIdx.x, wv = tid >> 6, ln = tid & 63;
    if (wv < NCH) {
        long long s = 0;
        for (int i = ln; i < NBINS; i += 64) s += counts[wv * NBINS + i];
        #pragma unroll
        for (int o = 32; o > 0; o >>= 1) s += __shfl_down(s, o, 64);
        if (ln == 0) s_tot[wv] = (float)s;
    }
    __syncthreads();
    for (int i = tid; i < NTOT; i += 512)
        wsf[i] = 1.0f - (float)counts[i] / s_tot[i / NBINS];
}

__device__ __forceinline__ void block_reduce_atomic(float acc, float scale, float* dst) {
    __shared__ float s_part[4];
    #pragma unroll
    for (int o = 32; o > 0; o >>= 1) acc += __shfl_down(acc, o, 64);
    int lane = threadIdx.x & 63, wid = threadIdx.x >> 6;
    if (lane == 0) s_part[wid] = acc;
    __syncthreads();
    if (threadIdx.x == 0)
        atomicAdd(dst, (s_part[0] + s_part[1] + s_part[2] + s_part[3]) * scale);
}

// Main: ALL 16 loads issued before anything else (pinned by sched_barrier),
// table staging + barrier overlap the load latency, then pure compute.
__global__ __launch_bounds__(BLOCK, 4) void k_main(const float4* __restrict__ in4,
                                                   const float4* __restrict__ tg4,
                                                   const float* __restrict__ wsf,
                                                   float* __restrict__ out) {
    __shared__ float s_w[NTOT];
    const int g = blockIdx.x * BLOCK + threadIdx.x;

    float4 a[NITER], b[NITER];
    #pragma unroll
    for (int t = 0; t < NITER; ++t) a[t] = in4[g + t * TTH];
    #pragma unroll
    for (int t = 0; t < NITER; ++t) b[t] = tg4[g + t * TTH];
    __builtin_amdgcn_sched_barrier(0);   // loads may not sink below this point

    for (int i = threadIdx.x; i < NTOT; i += BLOCK) s_w[i] = wsf[i];
    __syncthreads();

    const int c0 = (4 * g) % 5;          // same channel phase for all 8 trips
    int rb[4];
    #pragma unroll
    for (int j = 0; j < 4; ++j) { int c = c0 + j; if (c >= NCH) c -= NCH; rb[j] = c * NBINS + 100; }

    float acc = 0.0f;
    #pragma unroll
    for (int t = 0; t < NITER; ++t) {
        float xs[4] = {a[t].x, a[t].y, a[t].z, a[t].w};
        float ts[4] = {b[t].x, b[t].y, b[t].z, b[t].w};
        #pragma unroll
        for (int j = 0; j < 4; ++j) {
            float x  = xs[j];
            float kf = rintf(x * 10.0f);           // half-to-even == jnp.round
            float w  = 1.0f;
            if (kf >= -100.0f && kf <= 100.0f) w = s_w[rb[j] + (int)kf];
            float d = x - ts[j];
            acc = fmaf(w * d, d, acc);
        }
    }
    block_reduce_atomic(acc, 1.0f / (float)B_ELEMS, out);
}

extern "C" void kernel_launch(void* const* d_in, const int* in_sizes, int n_in,
                              void* d_out, int out_size, void* d_ws, size_t ws_size,
                              hipStream_t stream) {
    const float4* in4    = (const float4*)d_in[0];
    const float4* tg4    = (const float4*)d_in[1];
    const int*    counts = (const int*)d_in[3];
    float* wsf = (float*)d_ws;

    hipMemsetAsync(d_out, 0, sizeof(float), stream);
    k_table<<<1, 512, 0, stream>>>(counts, wsf);
    k_main <<<GRID, BLOCK, 0, stream>>>(in4, tg4, wsf, (float*)d_out);
}